// Round 9
// baseline (21.234 us; speedup 1.0000x reference)
//
#include <hip/hip_runtime.h>

#define N_NODES 1024
#define B_SZ 16
#define F_SZ 50

typedef float f32x4 __attribute__((ext_vector_type(4)));

// Kernel 1, two block ranges:
//  blocks [0, 64):    port_has_track bits per (b,n) -> bits[b*N+n].
//    port_feature_mask is a known constant 0/1 matrix (features 0-22
//    all-zero; port p sums exactly 7 features). Summing only nonzero
//    features in ascending-f order is bitwise identical to the reference's
//    masked accumulation (x + 0.0f == x exactly).
//  blocks [64, 1088): pack dir (i32, values 0..6) into 1 byte/entry:
//    p = adj<<6 | opp<<3 | d   (1 MB table, L2-resident everywhere).
__global__ __launch_bounds__(256) void prep_kernel(
        const float* __restrict__ nf,
        const int* __restrict__ dir,
        unsigned char* __restrict__ bits,
        unsigned char* __restrict__ pdir) {
    const int q = blockIdx.x;
    const int t = threadIdx.x;

    if (q < 64) {
        const int idx = q * 256 + t;           // b*N + n, 16384 total
        const float* r = nf + (size_t)idx * F_SZ;
        float f[27];
        #pragma unroll
        for (int x = 0; x < 27; ++x) f[x] = r[23 + x];  // features 23..49

        float a0 = (((((f[0]  + f[1])  + f[3])  + f[6])  + f[10]) + f[15]) + f[16];
        float a1 = (((((f[0]  + f[2])  + f[4])  + f[7])  + f[11]) + f[17]) + f[18];
        float a2 = (((((f[1]  + f[2])  + f[5])  + f[8])  + f[12]) + f[19]) + f[20];
        float a3 = (((((f[3]  + f[4])  + f[5])  + f[9])  + f[13]) + f[21]) + f[22];
        float a4 = (((((f[6]  + f[7])  + f[8])  + f[9])  + f[14]) + f[23]) + f[24];
        float a5 = (((((f[10] + f[11]) + f[12]) + f[13]) + f[14]) + f[25]) + f[26];

        unsigned m = 0;
        m |= (a0 > 0.0f) ? 1u  : 0u;
        m |= (a1 > 0.0f) ? 2u  : 0u;
        m |= (a2 > 0.0f) ? 4u  : 0u;
        m |= (a3 > 0.0f) ? 8u  : 0u;
        m |= (a4 > 0.0f) ? 16u : 0u;
        m |= (a5 > 0.0f) ? 32u : 0u;
        bits[idx] = (unsigned char)m;
    } else {
        const int e4 = (q - 64) * 256 + t;     // 262144 uchar4 slots
        int4 d = ((const int4*)dir)[e4];
        int dv[4] = {d.x, d.y, d.z, d.w};
        unsigned pk[4];
        #pragma unroll
        for (int k = 0; k < 4; ++k) {
            int dval = dv[k];
            unsigned adj = (dval != 6) ? 1u : 0u;
            unsigned ds = (unsigned)min(dval, 5);
            unsigned os = (unsigned)min((dval + 3) % 6, 5);
            pk[k] = (adj << 6) | (os << 3) | ds;
        }
        uchar4 o;
        o.x = (unsigned char)pk[0]; o.y = (unsigned char)pk[1];
        o.z = (unsigned char)pk[2]; o.w = (unsigned char)pk[3];
        ((uchar4*)pdir)[e4] = o;
    }
}

// Kernel 2: out[b,i,j] = src_bit(b,i,d) & dst_bit(b,j,o) & adj
// Fill-kernel-shaped: one (b,i) row per block (4 KB), one f32x4 per thread,
// PLAIN stores (match the 6.5 TB/s fill exactly). Reads: 4B packed dir +
// 4B dst bits per 16B written, all L2-resident (pdir 1 MB, bits 16 KB).
__global__ __launch_bounds__(256) void connect_kernel(
        const unsigned char* __restrict__ pdir,
        const unsigned char* __restrict__ bits,
        float* __restrict__ out) {
    const int bi = blockIdx.x;          // 16384 blocks = (b, i)
    const int t = threadIdx.x;          // columns [4t, 4t+3]
    const int b = bi >> 10;
    const int i = bi & (N_NODES - 1);

    uchar4 p4 = ((const uchar4*)(pdir + (size_t)i * N_NODES))[t];
    uchar4 t4 = ((const uchar4*)(bits + b * N_NODES))[t];
    const unsigned s = bits[b * N_NODES + i];   // block-uniform
    unsigned pv[4] = {p4.x, p4.y, p4.z, p4.w};
    unsigned tv[4] = {t4.x, t4.y, t4.z, t4.w};

    f32x4 o;
    #pragma unroll
    for (int k = 0; k < 4; ++k) {
        unsigned p = pv[k];
        o[k] = ((s >> (p & 7u)) & (tv[k] >> ((p >> 3) & 7u)) & (p >> 6) & 1u)
                   ? 1.0f : 0.0f;
    }
    *((f32x4*)(out + (size_t)bi * N_NODES) + t) = o;
}

extern "C" void kernel_launch(void* const* d_in, const int* in_sizes, int n_in,
                              void* d_out, int out_size, void* d_ws, size_t ws_size,
                              hipStream_t stream) {
    const float* nf  = (const float*)d_in[0];    // (16, 1024, 50) f32
    const int*   dir = (const int*)d_in[1];      // (1024, 1024) i32
    float* out = (float*)d_out;                  // (16, 1024, 1024) f32
    unsigned char* bits = (unsigned char*)d_ws;          // 16 KB  [b][n]
    unsigned char* pdir = (unsigned char*)d_ws + 16384;  // 1 MB packed dir

    prep_kernel<<<64 + 1024, 256, 0, stream>>>(nf, dir, bits, pdir);
    connect_kernel<<<B_SZ * N_NODES, 256, 0, stream>>>(pdir, bits, out);
}